// Round 1
// baseline (171.822 us; speedup 1.0000x reference)
//
#include <hip/hip_runtime.h>
#include <hip/hip_bf16.h>
#include <cstdint>

typedef unsigned int u32;
typedef unsigned short ushort_t;
typedef __attribute__((ext_vector_type(8))) __bf16 bf16x8;
typedef __attribute__((ext_vector_type(4))) float f32x4;
typedef __attribute__((ext_vector_type(2))) _Float16 half2_t;

#define BT_N 256
#define F_N 256
#define C_N 256
#define H_N 4
#define D_N 64
#define TC_N 768
#define M_N (BT_N * F_N)   // 65536

__device__ __forceinline__ ushort f2bf(float f) {
  u32 u = __float_as_uint(f);
  u32 r = (u + 0x7fffu + ((u >> 16) & 1u)) >> 16;
  return (ushort)r;
}

__device__ __forceinline__ half2_t u2h(u32 u) {
  return __builtin_bit_cast(half2_t, u);
}

__device__ __forceinline__ void store_out(_Float16* p, float v) { *p = (_Float16)v; }
__device__ __forceinline__ void store_out(float* p, float v) { *p = v; }

__device__ __forceinline__ void gload_lds16(const ushort* g, ushort* l) {
  __builtin_amdgcn_global_load_lds(
      (const __attribute__((address_space(1))) u32*)g,
      (__attribute__((address_space(3))) u32*)l, 16, 0, 0);
}

// ---------------------------------------------------------------------------
// fp32 -> bf16 conversion (for weights)
// ---------------------------------------------------------------------------
__global__ __launch_bounds__(256) void cvt_f32_bf16_k(
    const float* __restrict__ src, ushort* __restrict__ dst, int n4) {
  int idx = blockIdx.x * 256 + threadIdx.x;
  int stride = gridDim.x * 256;
  for (int i = idx; i < n4; i += stride) {
    float4 v = ((const float4*)src)[i];
    u32 a = (u32)f2bf(v.x) | ((u32)f2bf(v.y) << 16);
    u32 b = (u32)f2bf(v.z) | ((u32)f2bf(v.w) << 16);
    ((uint2*)dst)[i] = make_uint2(a, b);
  }
}

// ---------------------------------------------------------------------------
// GEMM: C[m][n] = sum_k A[m][k] * B[n][k] + bias[n]
// A: fp32 (reg-staged + cvt) if AF32, else bf16 via global_load_lds
// B: bf16 row-major [N][K] via global_load_lds
// 128x128 block tile, BK=64, 4 waves (2x2), each wave 64x64 via 4x4 mfma frags
// ---------------------------------------------------------------------------
template <bool AF32, typename OutT>
__global__ __launch_bounds__(256) void gemm_bt(
    const void* __restrict__ Ap, const ushort* __restrict__ Bp,
    const float* __restrict__ bias, OutT* __restrict__ Cp,
    int N, int K, int NTN) {
  __shared__ ushort As[128 * 64];
  __shared__ ushort Bs[128 * 64];
  const int tid = threadIdx.x;
  const int lane = tid & 63;
  const int wid = tid >> 6;
  const int wr = wid >> 1, wc = wid & 1;
  const int l15 = lane & 15, l4 = lane >> 4;
  const int bid = blockIdx.x;
  const int tm = bid / NTN;
  const int tn = bid - tm * NTN;
  const int rowBase = tm * 128, colBase = tn * 128;

  f32x4 acc[4][4] = {};

  for (int k0 = 0; k0 < K; k0 += 64) {
#pragma unroll
    for (int c = 0; c < 4; ++c) {
      int idx = c * 256 + tid;
      int r = idx >> 3;
      int kk = (idx & 7) << 3;
      if constexpr (AF32) {
        const float* ga = (const float*)Ap + (size_t)(rowBase + r) * K + k0 + kk;
        float4 f0 = *(const float4*)ga;
        float4 f1 = *(const float4*)(ga + 4);
        u32 p0 = (u32)f2bf(f0.x) | ((u32)f2bf(f0.y) << 16);
        u32 p1 = (u32)f2bf(f0.z) | ((u32)f2bf(f0.w) << 16);
        u32 p2 = (u32)f2bf(f1.x) | ((u32)f2bf(f1.y) << 16);
        u32 p3 = (u32)f2bf(f1.z) | ((u32)f2bf(f1.w) << 16);
        ((uint4*)As)[idx] = make_uint4(p0, p1, p2, p3);
      } else {
        const ushort* ga = (const ushort*)Ap + (size_t)(rowBase + r) * K + k0 + kk;
        gload_lds16(ga, As + (size_t)(c * 256 + (wid << 6)) * 8);
      }
      const ushort* gb = Bp + (size_t)(colBase + r) * K + k0 + kk;
      gload_lds16(gb, Bs + (size_t)(c * 256 + (wid << 6)) * 8);
    }
    __syncthreads();
#pragma unroll
    for (int kk = 0; kk < 2; ++kk) {
      bf16x8 af[4];
      bf16x8 bfr[4];
#pragma unroll
      for (int i2 = 0; i2 < 4; ++i2)
        af[i2] = *(const bf16x8*)(As + ((wr * 64 + i2 * 16 + l15) * 64 + kk * 32 + l4 * 8));
#pragma unroll
      for (int j2 = 0; j2 < 4; ++j2)
        bfr[j2] = *(const bf16x8*)(Bs + ((wc * 64 + j2 * 16 + l15) * 64 + kk * 32 + l4 * 8));
#pragma unroll
      for (int i2 = 0; i2 < 4; ++i2)
#pragma unroll
        for (int j2 = 0; j2 < 4; ++j2)
          acc[i2][j2] = __builtin_amdgcn_mfma_f32_16x16x32_bf16(
              af[i2], bfr[j2], acc[i2][j2], 0, 0, 0);
    }
    __syncthreads();
  }

  // epilogue: D row = (lane>>4)*4 + r, col = lane&15 within each 16x16 tile
#pragma unroll
  for (int j2 = 0; j2 < 4; ++j2) {
    int col = colBase + wc * 64 + j2 * 16 + l15;
    float bv = bias[col];
#pragma unroll
    for (int i2 = 0; i2 < 4; ++i2) {
      int row0 = rowBase + wr * 64 + i2 * 16 + l4 * 4;
#pragma unroll
      for (int r = 0; r < 4; ++r) {
        float v = acc[i2][j2][r] + bv;
        store_out(Cp + (size_t)(row0 + r) * N + col, v);
      }
    }
  }
}

// ---------------------------------------------------------------------------
// Banded attention: one block per (bt, h). 256 threads, one output row each.
// qkv rows: [ q(256) | k(256) | v(256) ] in f16; head h occupies cols h*64..
// K/V staged in LDS (f16), row stride 33 dwords (66 halves) -> conflict-free.
// No max-subtraction softmax (scores ~N(0,1), exp safe in fp32).
// ---------------------------------------------------------------------------
__global__ __launch_bounds__(256) void attn_banded(
    const _Float16* __restrict__ qkv, ushort* __restrict__ aout) {
  __shared__ u32 kbuf[256 * 33];
  __shared__ u32 vbuf[256 * 33];
  const int tid = threadIdx.x;
  const int blk = blockIdx.x;
  const int bt = blk >> 2;
  const int h = blk & 3;
  const _Float16* base = qkv + (size_t)bt * F_N * TC_N + h * D_N;

#pragma unroll
  for (int p = 0; p < 8; ++p) {
    int r = p * 32 + (tid >> 3);
    int c4 = (tid & 7) * 4;  // dword index within row (0..28)
    const uint4 k4 = *(const uint4*)(base + (size_t)r * TC_N + C_N + c4 * 2);
    const uint4 v4 = *(const uint4*)(base + (size_t)r * TC_N + 2 * C_N + c4 * 2);
    int lo = r * 33 + c4;
    kbuf[lo + 0] = k4.x; kbuf[lo + 1] = k4.y; kbuf[lo + 2] = k4.z; kbuf[lo + 3] = k4.w;
    vbuf[lo + 0] = v4.x; vbuf[lo + 1] = v4.y; vbuf[lo + 2] = v4.z; vbuf[lo + 3] = v4.w;
  }

  const int i = tid;
  half2_t qh[32];
  {
    const uint4* gq = (const uint4*)(base + (size_t)i * TC_N);
#pragma unroll
    for (int c = 0; c < 8; ++c) {
      uint4 t4 = gq[c];
      qh[c * 4 + 0] = u2h(t4.x);
      qh[c * 4 + 1] = u2h(t4.y);
      qh[c * 4 + 2] = u2h(t4.z);
      qh[c * 4 + 3] = u2h(t4.w);
    }
  }
  __syncthreads();

  float l = 0.f;
  half2_t outh[32];
  const _Float16 z0 = (_Float16)0.f;
#pragma unroll
  for (int t = 0; t < 32; ++t) outh[t] = half2_t{z0, z0};

#pragma unroll 1
  for (int jo = 0; jo < 33; ++jo) {
    int j = i - 16 + jo;
    int jc = j < 0 ? 0 : (j > 255 ? 255 : j);
    const u32* kr = kbuf + jc * 33;
    float s0 = 0.f, s1 = 0.f, s2 = 0.f, s3 = 0.f;
#pragma unroll
    for (int t = 0; t < 8; ++t) {
      s0 = __builtin_amdgcn_fdot2(u2h(kr[4 * t + 0]), qh[4 * t + 0], s0, false);
      s1 = __builtin_amdgcn_fdot2(u2h(kr[4 * t + 1]), qh[4 * t + 1], s1, false);
      s2 = __builtin_amdgcn_fdot2(u2h(kr[4 * t + 2]), qh[4 * t + 2], s2, false);
      s3 = __builtin_amdgcn_fdot2(u2h(kr[4 * t + 3]), qh[4 * t + 3], s3, false);
    }
    float s = (s0 + s1) + (s2 + s3);
    float p = (j == jc) ? __expf(s * 0.125f) : 0.f;
    l += p;
    _Float16 pf = (_Float16)p;
    half2_t ph = {pf, pf};
    const u32* vr = vbuf + jc * 33;
#pragma unroll
    for (int t = 0; t < 32; ++t)
      outh[t] = u2h(vr[t]) * ph + outh[t];
  }

  float inv = 1.f / l;
  u32* orow = (u32*)(aout + (size_t)(bt * F_N + i) * C_N + h * D_N);
#pragma unroll
  for (int t = 0; t < 32; ++t) {
    float o0 = (float)outh[t][0] * inv;
    float o1 = (float)outh[t][1] * inv;
    orow[t] = (u32)f2bf(o0) | ((u32)f2bf(o1) << 16);
  }
}

// ---------------------------------------------------------------------------
extern "C" void kernel_launch(void* const* d_in, const int* in_sizes, int n_in,
                              void* d_out, int out_size, void* d_ws, size_t ws_size,
                              hipStream_t stream) {
  const float* x = (const float*)d_in[0];
  const float* w_in = (const float*)d_in[1];
  const float* b_in = (const float*)d_in[2];
  const float* w_out = (const float*)d_in[3];
  const float* b_out = (const float*)d_in[4];
  float* y = (float*)d_out;

  char* ws = (char*)d_ws;
  const size_t qkv_bytes = (size_t)M_N * TC_N * 2;      // 100,663,296
  const size_t attn_bytes = (size_t)M_N * C_N * 2;      // 33,554,432
  _Float16* qkv = (_Float16*)ws;
  ushort* attn = (ushort*)(ws + qkv_bytes);
  ushort* winb = (ushort*)(ws + qkv_bytes + attn_bytes);
  ushort* woutb = winb + TC_N * C_N;

  // weights fp32 -> bf16
  cvt_f32_bf16_k<<<192, 256, 0, stream>>>(w_in, winb, TC_N * C_N / 4);
  cvt_f32_bf16_k<<<64, 256, 0, stream>>>(w_out, woutb, C_N * C_N / 4);

  // qkv = x @ w_in^T + b_in   (f16 out)
  gemm_bt<true, _Float16><<<(M_N / 128) * (TC_N / 128), 256, 0, stream>>>(
      x, winb, b_in, qkv, TC_N, C_N, TC_N / 128);

  // banded attention (bf16 out)
  attn_banded<<<BT_N * H_N, 256, 0, stream>>>(qkv, attn);

  // y = attn @ w_out^T + b_out  (fp32 out)
  gemm_bt<false, float><<<(M_N / 128) * (C_N / 128), 256, 0, stream>>>(
      attn, woutb, b_out, y, C_N, C_N, C_N / 128);
}

// Round 3
// 145.029 us; speedup vs baseline: 1.1847x; 1.1847x over previous
//
#include <hip/hip_runtime.h>
#include <hip/hip_bf16.h>
#include <cstdint>

typedef unsigned int u32;
typedef __attribute__((ext_vector_type(8))) __bf16 bf16x8;
typedef __attribute__((ext_vector_type(4))) float f32x4;
typedef __attribute__((ext_vector_type(2))) _Float16 half2_t;

#define BT_N 256
#define F_N 256
#define C_N 256
#define H_N 4
#define D_N 64
#define TC_N 768
#define M_N (BT_N * F_N)   // 65536

__device__ __forceinline__ ushort f2bf(float f) {
  u32 u = __float_as_uint(f);
  u32 r = (u + 0x7fffu + ((u >> 16) & 1u)) >> 16;
  return (ushort)r;
}

__device__ __forceinline__ half2_t u2h(u32 u) {
  return __builtin_bit_cast(half2_t, u);
}

__device__ __forceinline__ void store_out(_Float16* p, float v) { *p = (_Float16)v; }
__device__ __forceinline__ void store_out(float* p, float v) { *p = v; }

__device__ __forceinline__ void gload_lds16(const ushort* g, ushort* l) {
  __builtin_amdgcn_global_load_lds(
      (const __attribute__((address_space(1))) u32*)g,
      (__attribute__((address_space(3))) u32*)l, 16, 0, 0);
}

// ---------------------------------------------------------------------------
// fp32 -> bf16 conversion (grid-strided over one or two source arrays)
// ---------------------------------------------------------------------------
__global__ __launch_bounds__(256) void cvt_f32_bf16_k(
    const float* __restrict__ src, ushort* __restrict__ dst, int n4) {
  int idx = blockIdx.x * 256 + threadIdx.x;
  int stride = gridDim.x * 256;
  for (int i = idx; i < n4; i += stride) {
    float4 v = ((const float4*)src)[i];
    u32 a = (u32)f2bf(v.x) | ((u32)f2bf(v.y) << 16);
    u32 b = (u32)f2bf(v.z) | ((u32)f2bf(v.w) << 16);
    ((uint2*)dst)[i] = make_uint2(a, b);
  }
}

__global__ __launch_bounds__(256) void cvt2_f32_bf16_k(
    const float* __restrict__ s0, ushort* __restrict__ d0, int n0,
    const float* __restrict__ s1, ushort* __restrict__ d1, int n1) {
  int idx = blockIdx.x * 256 + threadIdx.x;
  int stride = gridDim.x * 256;
  for (int i = idx; i < n0 + n1; i += stride) {
    const float4* s = (i < n0) ? ((const float4*)s0 + i) : ((const float4*)s1 + (i - n0));
    ushort* d = (i < n0) ? (d0 + (size_t)i * 4) : (d1 + (size_t)(i - n0) * 4);
    float4 v = *s;
    u32 a = (u32)f2bf(v.x) | ((u32)f2bf(v.y) << 16);
    u32 b = (u32)f2bf(v.z) | ((u32)f2bf(v.w) << 16);
    *(uint2*)d = make_uint2(a, b);
  }
}

// ---------------------------------------------------------------------------
// GEMM: C[m][n] = sum_k A[m][k] * B[n][k] + bias[n]
// A,B bf16 row-major via global_load_lds(16B). 128x128 tile, BK=64, 4 waves.
// XCD-aware block swizzle (requires gridDim % 8 == 0).
// ---------------------------------------------------------------------------
template <typename OutT>
__global__ __launch_bounds__(256) void gemm_bt(
    const ushort* __restrict__ Ap, const ushort* __restrict__ Bp,
    const float* __restrict__ bias, OutT* __restrict__ Cp,
    int N, int K, int NTN, int nwg8) {
  __shared__ ushort As[128 * 64];
  __shared__ ushort Bs[128 * 64];
  const int tid = threadIdx.x;
  const int lane = tid & 63;
  const int wid = tid >> 6;
  const int wr = wid >> 1, wc = wid & 1;
  const int l15 = lane & 15, l4 = lane >> 4;
  const int b = blockIdx.x;
  const int bid = (b & 7) * nwg8 + (b >> 3);   // XCD swizzle (bijective: nwg%8==0)
  const int tm = bid / NTN;
  const int tn = bid - tm * NTN;
  const int rowBase = tm * 128, colBase = tn * 128;

  f32x4 acc[4][4] = {};

  for (int k0 = 0; k0 < K; k0 += 64) {
#pragma unroll
    for (int c = 0; c < 4; ++c) {
      int idx = c * 256 + tid;
      int r = idx >> 3;
      int kk = (idx & 7) << 3;
      gload_lds16(Ap + (size_t)(rowBase + r) * K + k0 + kk,
                  As + (size_t)(c * 256 + (wid << 6)) * 8);
      gload_lds16(Bp + (size_t)(colBase + r) * K + k0 + kk,
                  Bs + (size_t)(c * 256 + (wid << 6)) * 8);
    }
    __syncthreads();
#pragma unroll
    for (int kk = 0; kk < 2; ++kk) {
      bf16x8 af[4];
      bf16x8 bfr[4];
#pragma unroll
      for (int i2 = 0; i2 < 4; ++i2)
        af[i2] = *(const bf16x8*)(As + ((wr * 64 + i2 * 16 + l15) * 64 + kk * 32 + l4 * 8));
#pragma unroll
      for (int j2 = 0; j2 < 4; ++j2)
        bfr[j2] = *(const bf16x8*)(Bs + ((wc * 64 + j2 * 16 + l15) * 64 + kk * 32 + l4 * 8));
#pragma unroll
      for (int i2 = 0; i2 < 4; ++i2)
#pragma unroll
        for (int j2 = 0; j2 < 4; ++j2)
          acc[i2][j2] = __builtin_amdgcn_mfma_f32_16x16x32_bf16(
              af[i2], bfr[j2], acc[i2][j2], 0, 0, 0);
    }
    __syncthreads();
  }

  // epilogue: D row = (lane>>4)*4 + r, col = lane&15 within each 16x16 tile
#pragma unroll
  for (int j2 = 0; j2 < 4; ++j2) {
    int col = colBase + wc * 64 + j2 * 16 + l15;
    float bv = bias[col];
#pragma unroll
    for (int i2 = 0; i2 < 4; ++i2) {
      int row0 = rowBase + wr * 64 + i2 * 16 + l4 * 4;
#pragma unroll
      for (int r = 0; r < 4; ++r) {
        float v = acc[i2][j2][r] + bv;
        store_out(Cp + (size_t)(row0 + r) * N + col, v);
      }
    }
  }
}

// ---------------------------------------------------------------------------
// Banded attention: one block per (bt, h). 256 threads.
// thread = (pair, half): pair owns rows 2p,2p+1; half owns 32 of 64 dims.
// Each K/V row read ONCE per row-pair (halves LDS traffic vs row-per-thread).
// LDS row stride 35 dwords, halves at dword offsets {0..15} and {17..32}:
// bank = (3*r + 17*hf + c) mod 32 -> worst 2-way (free).
// No max-subtraction softmax (scores ~N(0,1); exp safe in fp32).
// ---------------------------------------------------------------------------
__global__ __launch_bounds__(256) void attn_banded(
    const _Float16* __restrict__ qkv, ushort* __restrict__ aout) {
  __shared__ u32 kbuf[256 * 35];
  __shared__ u32 vbuf[256 * 35];
  const int tid = threadIdx.x;
  const int blk = blockIdx.x;
  const int bt = blk >> 2;
  const int h = blk & 3;
  const _Float16* base = qkv + (size_t)bt * F_N * TC_N + h * D_N;

  // stage K,V (head slice, 256x64 f16 each)
#pragma unroll
  for (int p = 0; p < 8; ++p) {
    int r = p * 32 + (tid >> 3);
    int c4 = (tid & 7) * 4;  // dword index within row: 0,4,...,28
    uint4 k4 = *(const uint4*)(base + (size_t)r * TC_N + 256 + c4 * 2);
    uint4 v4 = *(const uint4*)(base + (size_t)r * TC_N + 512 + c4 * 2);
    int slot = r * 35 + c4 + (c4 >= 16 ? 1 : 0);
    kbuf[slot + 0] = k4.x; kbuf[slot + 1] = k4.y; kbuf[slot + 2] = k4.z; kbuf[slot + 3] = k4.w;
    vbuf[slot + 0] = v4.x; vbuf[slot + 1] = v4.y; vbuf[slot + 2] = v4.z; vbuf[slot + 3] = v4.w;
  }

  const int pr = tid >> 1;
  const int hf = tid & 1;
  const int r0 = pr * 2, r1 = r0 + 1;

  half2_t q0[16], q1[16];
  {
    const uint4* g0 = (const uint4*)(base + (size_t)r0 * TC_N + hf * 32);
    const uint4* g1 = (const uint4*)(base + (size_t)r1 * TC_N + hf * 32);
#pragma unroll
    for (int c = 0; c < 4; ++c) {
      uint4 a = g0[c], d = g1[c];
      q0[c * 4 + 0] = u2h(a.x); q0[c * 4 + 1] = u2h(a.y);
      q0[c * 4 + 2] = u2h(a.z); q0[c * 4 + 3] = u2h(a.w);
      q1[c * 4 + 0] = u2h(d.x); q1[c * 4 + 1] = u2h(d.y);
      q1[c * 4 + 2] = u2h(d.z); q1[c * 4 + 3] = u2h(d.w);
    }
  }
  __syncthreads();

  float l0 = 0.f, l1 = 0.f;
  half2_t o0[16], o1[16];
  const _Float16 z0 = (_Float16)0.f;
#pragma unroll
  for (int t = 0; t < 16; ++t) { o0[t] = half2_t{z0, z0}; o1[t] = half2_t{z0, z0}; }

#pragma unroll 1
  for (int jo = 0; jo < 34; ++jo) {
    int j = r0 - 16 + jo;  // union of bands of rows r0,r1
    int jc = j < 0 ? 0 : (j > 255 ? 255 : j);
    const u32* kr = kbuf + jc * 35 + hf * 17;
    float s0a = 0.f, s0b = 0.f, s1a = 0.f, s1b = 0.f;
#pragma unroll
    for (int t = 0; t < 8; ++t) {
      half2_t ka = u2h(kr[2 * t]);
      half2_t kb = u2h(kr[2 * t + 1]);
      s0a = __builtin_amdgcn_fdot2(ka, q0[2 * t], s0a, false);
      s0b = __builtin_amdgcn_fdot2(kb, q0[2 * t + 1], s0b, false);
      s1a = __builtin_amdgcn_fdot2(ka, q1[2 * t], s1a, false);
      s1b = __builtin_amdgcn_fdot2(kb, q1[2 * t + 1], s1b, false);
    }
    float s0p = s0a + s0b, s1p = s1a + s1b;
    s0p += __shfl_xor(s0p, 1, 64);
    s1p += __shfl_xor(s1p, 1, 64);
    bool ok = (j >= 0) && (j < 256);
    float p0 = (ok && jo < 33) ? __expf(s0p * 0.125f) : 0.f;  // |j-r0|<=16
    float p1 = (ok && jo > 0) ? __expf(s1p * 0.125f) : 0.f;   // |j-r1|<=16
    l0 += p0; l1 += p1;
    _Float16 pf0 = (_Float16)p0, pf1 = (_Float16)p1;
    half2_t ph0 = {pf0, pf0}, ph1 = {pf1, pf1};
    const u32* vr = vbuf + jc * 35 + hf * 17;
#pragma unroll
    for (int t = 0; t < 16; ++t) {
      half2_t vh = u2h(vr[t]);
      o0[t] = vh * ph0 + o0[t];
      o1[t] = vh * ph1 + o1[t];
    }
  }

  float i0 = 1.f / l0, i1 = 1.f / l1;
  u32 w0[16], w1[16];
#pragma unroll
  for (int t = 0; t < 16; ++t) {
    w0[t] = (u32)f2bf((float)o0[t][0] * i0) | ((u32)f2bf((float)o0[t][1] * i0) << 16);
    w1[t] = (u32)f2bf((float)o1[t][0] * i1) | ((u32)f2bf((float)o1[t][1] * i1) << 16);
  }
  u32* d0 = (u32*)(aout + (size_t)(bt * F_N + r0) * C_N + h * D_N + hf * 32);
  u32* d1 = (u32*)(aout + (size_t)(bt * F_N + r1) * C_N + h * D_N + hf * 32);
#pragma unroll
  for (int c = 0; c < 4; ++c) {
    ((uint4*)d0)[c] = make_uint4(w0[4 * c], w0[4 * c + 1], w0[4 * c + 2], w0[4 * c + 3]);
    ((uint4*)d1)[c] = make_uint4(w1[4 * c], w1[4 * c + 1], w1[4 * c + 2], w1[4 * c + 3]);
  }
}

// ---------------------------------------------------------------------------
extern "C" void kernel_launch(void* const* d_in, const int* in_sizes, int n_in,
                              void* d_out, int out_size, void* d_ws, size_t ws_size,
                              hipStream_t stream) {
  const float* x = (const float*)d_in[0];
  const float* w_in = (const float*)d_in[1];
  const float* b_in = (const float*)d_in[2];
  const float* w_out = (const float*)d_in[3];
  const float* b_out = (const float*)d_in[4];
  float* y = (float*)d_out;

  char* ws = (char*)d_ws;
  const size_t qkv_bytes = (size_t)M_N * TC_N * 2;   // 100.7 MB
  const size_t xb_bytes = (size_t)M_N * C_N * 2;     // 33.6 MB (aliased: xb then attn)
  _Float16* qkv = (_Float16*)ws;
  ushort* xb = (ushort*)(ws + qkv_bytes);            // x as bf16; dead after gemm1
  ushort* attn = xb;                                 // attn overwrites xb (safe: after gemm1)
  ushort* winb = (ushort*)(ws + qkv_bytes + xb_bytes);
  ushort* woutb = winb + TC_N * C_N;

  // weights fp32 -> bf16 (one launch), x fp32 -> bf16
  cvt2_f32_bf16_k<<<128, 256, 0, stream>>>(w_in, winb, TC_N * C_N / 4,
                                           w_out, woutb, C_N * C_N / 4);
  cvt_f32_bf16_k<<<2048, 256, 0, stream>>>(x, xb, M_N * C_N / 4);

  // qkv = x @ w_in^T + b_in   (f16 out)
  gemm_bt<_Float16><<<(M_N / 128) * (TC_N / 128), 256, 0, stream>>>(
      xb, winb, b_in, qkv, TC_N, C_N, TC_N / 128, (M_N / 128) * (TC_N / 128) / 8);

  // banded attention (bf16 out)
  attn_banded<<<BT_N * H_N, 256, 0, stream>>>(qkv, attn);

  // y = attn @ w_out^T + b_out  (fp32 out)
  gemm_bt<float><<<(M_N / 128) * (C_N / 128), 256, 0, stream>>>(
      attn, woutb, b_out, y, C_N, C_N, C_N / 128, (M_N / 128) * (C_N / 128) / 8);
}

// Round 4
// 136.097 us; speedup vs baseline: 1.2625x; 1.0656x over previous
//
#include <hip/hip_runtime.h>
#include <hip/hip_bf16.h>
#include <cstdint>

typedef unsigned int u32;
typedef __attribute__((ext_vector_type(8))) __bf16 bf16x8;
typedef __attribute__((ext_vector_type(4))) float f32x4;
typedef __attribute__((ext_vector_type(2))) _Float16 half2_t;

#define BT_N 256
#define F_N 256
#define C_N 256
#define H_N 4
#define D_N 64
#define TC_N 768
#define M_N (BT_N * F_N)   // 65536

__device__ __forceinline__ ushort f2bf(float f) {
  u32 u = __float_as_uint(f);
  u32 r = (u + 0x7fffu + ((u >> 16) & 1u)) >> 16;
  return (ushort)r;
}

__device__ __forceinline__ half2_t u2h(u32 u) {
  return __builtin_bit_cast(half2_t, u);
}

__device__ __forceinline__ void gload_lds16(const ushort* g, ushort* l) {
  __builtin_amdgcn_global_load_lds(
      (const __attribute__((address_space(1))) u32*)g,
      (__attribute__((address_space(3))) u32*)l, 16, 0, 0);
}

// ---------------------------------------------------------------------------
// fp32 -> bf16 conversion
// ---------------------------------------------------------------------------
__global__ __launch_bounds__(256) void cvt_f32_bf16_k(
    const float* __restrict__ src, ushort* __restrict__ dst, int n4) {
  int idx = blockIdx.x * 256 + threadIdx.x;
  int stride = gridDim.x * 256;
  for (int i = idx; i < n4; i += stride) {
    float4 v = ((const float4*)src)[i];
    u32 a = (u32)f2bf(v.x) | ((u32)f2bf(v.y) << 16);
    u32 b = (u32)f2bf(v.z) | ((u32)f2bf(v.w) << 16);
    ((uint2*)dst)[i] = make_uint2(a, b);
  }
}

__global__ __launch_bounds__(256) void cvt2_f32_bf16_k(
    const float* __restrict__ s0, ushort* __restrict__ d0, int n0,
    const float* __restrict__ s1, ushort* __restrict__ d1, int n1) {
  int idx = blockIdx.x * 256 + threadIdx.x;
  int stride = gridDim.x * 256;
  for (int i = idx; i < n0 + n1; i += stride) {
    const float4* s = (i < n0) ? ((const float4*)s0 + i) : ((const float4*)s1 + (i - n0));
    ushort* d = (i < n0) ? (d0 + (size_t)i * 4) : (d1 + (size_t)(i - n0) * 4);
    float4 v = *s;
    u32 a = (u32)f2bf(v.x) | ((u32)f2bf(v.y) << 16);
    u32 b = (u32)f2bf(v.z) | ((u32)f2bf(v.w) << 16);
    *(uint2*)d = make_uint2(a, b);
  }
}

// ---------------------------------------------------------------------------
// GEMM: C[m][n] = sum_k A[m][k]*B[n][k] + bias[n].  K=256 fixed.
// 128x128 tile, BK=64, double-buffered LDS, 2-phase pipeline (stage t+1
// issued before compute t, ONE barrier per K-step).  Epilogue via LDS for
// coalesced stores.  XCD swizzle (grid % 8 == 0).
// ---------------------------------------------------------------------------
template <typename OutT>
__global__ __launch_bounds__(256, 2) void gemm_bt(
    const ushort* __restrict__ Ap, const ushort* __restrict__ Bp,
    const float* __restrict__ bias, OutT* __restrict__ Cp,
    int N, int NTN, int nwg8) {
  constexpr bool F32OUT = (sizeof(OutT) == 4);
  constexpr int SMEM_BYTES = F32OUT ? 67584 : 65536;  // max(staging 64K, epi)
  __shared__ char smem[SMEM_BYTES];
  ushort* smemH = (ushort*)smem;

  const int tid = threadIdx.x;
  const int lane = tid & 63;
  const int wid = tid >> 6;
  const int wr = wid >> 1, wc = wid & 1;
  const int l15 = lane & 15, l4 = lane >> 4;
  const int b = blockIdx.x;
  const int bid = (b & 7) * nwg8 + (b >> 3);
  const int tm = bid / NTN;
  const int tn = bid - tm * NTN;
  const int rowBase = tm * 128, colBase = tn * 128;

  f32x4 acc[4][4] = {};

  // staging buffers: A(buf) @ buf*8192 halves, B(buf) @ 16384 + buf*8192
  const int ar = (tid >> 3);            // row within tile this thread loads
  const int akk = (tid & 7) << 3;       // k-offset (halves)
  const ushort* gA = Ap + (size_t)(rowBase + ar) * 256 + akk;
  const ushort* gB = Bp + (size_t)(colBase + ar) * 256 + akk;

#define STAGE(buf, k0)                                                        \
  {                                                                           \
    ushort* As_ = smemH + (buf) * 8192;                                       \
    ushort* Bs_ = smemH + 16384 + (buf) * 8192;                               \
    _Pragma("unroll") for (int c = 0; c < 4; ++c) {                           \
      gload_lds16(gA + (size_t)(c * 32) * 256 + (k0),                         \
                  As_ + (size_t)(c * 256 + (wid << 6)) * 8);                  \
      gload_lds16(gB + (size_t)(c * 32) * 256 + (k0),                         \
                  Bs_ + (size_t)(c * 256 + (wid << 6)) * 8);                  \
    }                                                                         \
  }

  STAGE(0, 0);
  int cur = 0;
#pragma unroll
  for (int t = 0; t < 4; ++t) {
    __syncthreads();                    // drains vmcnt: buf[cur] ready
    if (t < 3) STAGE(cur ^ 1, (t + 1) * 64);
    const ushort* As_ = smemH + cur * 8192;
    const ushort* Bs_ = smemH + 16384 + cur * 8192;
#pragma unroll
    for (int kk = 0; kk < 2; ++kk) {
      bf16x8 af[4];
      bf16x8 bfr[4];
#pragma unroll
      for (int i2 = 0; i2 < 4; ++i2)
        af[i2] = *(const bf16x8*)(As_ + ((wr * 64 + i2 * 16 + l15) * 64 + kk * 32 + l4 * 8));
#pragma unroll
      for (int j2 = 0; j2 < 4; ++j2)
        bfr[j2] = *(const bf16x8*)(Bs_ + ((wc * 64 + j2 * 16 + l15) * 64 + kk * 32 + l4 * 8));
#pragma unroll
      for (int i2 = 0; i2 < 4; ++i2)
#pragma unroll
        for (int j2 = 0; j2 < 4; ++j2)
          acc[i2][j2] = __builtin_amdgcn_mfma_f32_16x16x32_bf16(
              af[i2], bfr[j2], acc[i2][j2], 0, 0, 0);
    }
    cur ^= 1;
  }
#undef STAGE

  // ---- epilogue via LDS (coalesced stores) ----
  __syncthreads();  // all waves done reading staging buffers
  if constexpr (F32OUT) {
    // LDS tile: 128 rows x 132 dwords (528B stride)
    float* eb = (float*)smem;
#pragma unroll
    for (int j2 = 0; j2 < 4; ++j2) {
      float bv = bias[colBase + wc * 64 + j2 * 16 + l15];
#pragma unroll
      for (int i2 = 0; i2 < 4; ++i2)
#pragma unroll
        for (int r = 0; r < 4; ++r)
          eb[(wr * 64 + i2 * 16 + l4 * 4 + r) * 132 + wc * 64 + j2 * 16 + l15] =
              acc[i2][j2][r] + bv;
    }
    __syncthreads();
    // one full row (512B) per wave-instruction: 64 lanes x 8B
#pragma unroll
    for (int i = 0; i < 32; ++i) {
      int row = wid * 32 + i;
      uint2 d = *(const uint2*)((const u32*)eb + row * 132 + lane * 2);
      *(uint2*)((float*)Cp + (size_t)(rowBase + row) * N + colBase + lane * 2) = d;
    }
  } else {
    // LDS tile: 128 rows x 136 halves (272B stride)
    ushort* eb = smemH;
#pragma unroll
    for (int j2 = 0; j2 < 4; ++j2) {
      float bv = bias[colBase + wc * 64 + j2 * 16 + l15];
#pragma unroll
      for (int i2 = 0; i2 < 4; ++i2)
#pragma unroll
        for (int r = 0; r < 4; ++r) {
          _Float16 h = (_Float16)(acc[i2][j2][r] + bv);
          eb[(wr * 64 + i2 * 16 + l4 * 4 + r) * 136 + wc * 64 + j2 * 16 + l15] =
              __builtin_bit_cast(ushort, h);
        }
    }
    __syncthreads();
    // 2 rows (256B each) per wave-instruction: 32 lanes x 8B per row
#pragma unroll
    for (int i = 0; i < 16; ++i) {
      int row = wid * 32 + 2 * i + (lane >> 5);
      int hl = lane & 31;
      uint2 d = *(const uint2*)(eb + row * 136 + hl * 4);
      *(uint2*)((_Float16*)Cp + (size_t)(rowBase + row) * N + colBase + hl * 4) = d;
    }
  }
}

// ---------------------------------------------------------------------------
// Banded attention: one block per (bt, h). 256 threads.
// thread = (pair, half): pair owns rows 2p,2p+1; half owns 32 of 64 dims.
// ---------------------------------------------------------------------------
__global__ __launch_bounds__(256) void attn_banded(
    const _Float16* __restrict__ qkv, ushort* __restrict__ aout) {
  __shared__ u32 kbuf[256 * 35];
  __shared__ u32 vbuf[256 * 35];
  const int tid = threadIdx.x;
  const int blk = blockIdx.x;
  const int bt = blk >> 2;
  const int h = blk & 3;
  const _Float16* base = qkv + (size_t)bt * F_N * TC_N + h * D_N;

#pragma unroll
  for (int p = 0; p < 8; ++p) {
    int r = p * 32 + (tid >> 3);
    int c4 = (tid & 7) * 4;
    uint4 k4 = *(const uint4*)(base + (size_t)r * TC_N + 256 + c4 * 2);
    uint4 v4 = *(const uint4*)(base + (size_t)r * TC_N + 512 + c4 * 2);
    int slot = r * 35 + c4 + (c4 >= 16 ? 1 : 0);
    kbuf[slot + 0] = k4.x; kbuf[slot + 1] = k4.y; kbuf[slot + 2] = k4.z; kbuf[slot + 3] = k4.w;
    vbuf[slot + 0] = v4.x; vbuf[slot + 1] = v4.y; vbuf[slot + 2] = v4.z; vbuf[slot + 3] = v4.w;
  }

  const int pr = tid >> 1;
  const int hf = tid & 1;
  const int r0 = pr * 2, r1 = r0 + 1;

  half2_t q0[16], q1[16];
  {
    const uint4* g0 = (const uint4*)(base + (size_t)r0 * TC_N + hf * 32);
    const uint4* g1 = (const uint4*)(base + (size_t)r1 * TC_N + hf * 32);
#pragma unroll
    for (int c = 0; c < 4; ++c) {
      uint4 a = g0[c], d = g1[c];
      q0[c * 4 + 0] = u2h(a.x); q0[c * 4 + 1] = u2h(a.y);
      q0[c * 4 + 2] = u2h(a.z); q0[c * 4 + 3] = u2h(a.w);
      q1[c * 4 + 0] = u2h(d.x); q1[c * 4 + 1] = u2h(d.y);
      q1[c * 4 + 2] = u2h(d.z); q1[c * 4 + 3] = u2h(d.w);
    }
  }
  __syncthreads();

  float l0 = 0.f, l1 = 0.f;
  half2_t o0[16], o1[16];
  const _Float16 z0 = (_Float16)0.f;
#pragma unroll
  for (int t = 0; t < 16; ++t) { o0[t] = half2_t{z0, z0}; o1[t] = half2_t{z0, z0}; }

#pragma unroll 1
  for (int jo = 0; jo < 34; ++jo) {
    int j = r0 - 16 + jo;
    int jc = j < 0 ? 0 : (j > 255 ? 255 : j);
    const u32* kr = kbuf + jc * 35 + hf * 17;
    float s0a = 0.f, s0b = 0.f, s1a = 0.f, s1b = 0.f;
#pragma unroll
    for (int t = 0; t < 8; ++t) {
      half2_t ka = u2h(kr[2 * t]);
      half2_t kb = u2h(kr[2 * t + 1]);
      s0a = __builtin_amdgcn_fdot2(ka, q0[2 * t], s0a, false);
      s0b = __builtin_amdgcn_fdot2(kb, q0[2 * t + 1], s0b, false);
      s1a = __builtin_amdgcn_fdot2(ka, q1[2 * t], s1a, false);
      s1b = __builtin_amdgcn_fdot2(kb, q1[2 * t + 1], s1b, false);
    }
    float s0p = s0a + s0b, s1p = s1a + s1b;
    s0p += __shfl_xor(s0p, 1, 64);
    s1p += __shfl_xor(s1p, 1, 64);
    bool ok = (j >= 0) && (j < 256);
    float p0 = (ok && jo < 33) ? __expf(s0p * 0.125f) : 0.f;
    float p1 = (ok && jo > 0) ? __expf(s1p * 0.125f) : 0.f;
    l0 += p0; l1 += p1;
    _Float16 pf0 = (_Float16)p0, pf1 = (_Float16)p1;
    half2_t ph0 = {pf0, pf0}, ph1 = {pf1, pf1};
    const u32* vr = vbuf + jc * 35 + hf * 17;
#pragma unroll
    for (int t = 0; t < 16; ++t) {
      half2_t vh = u2h(vr[t]);
      o0[t] = vh * ph0 + o0[t];
      o1[t] = vh * ph1 + o1[t];
    }
  }

  float i0 = 1.f / l0, i1 = 1.f / l1;
  u32 w0[16], w1[16];
#pragma unroll
  for (int t = 0; t < 16; ++t) {
    w0[t] = (u32)f2bf((float)o0[t][0] * i0) | ((u32)f2bf((float)o0[t][1] * i0) << 16);
    w1[t] = (u32)f2bf((float)o1[t][0] * i1) | ((u32)f2bf((float)o1[t][1] * i1) << 16);
  }
  u32* d0 = (u32*)(aout + (size_t)(bt * F_N + r0) * C_N + h * D_N + hf * 32);
  u32* d1 = (u32*)(aout + (size_t)(bt * F_N + r1) * C_N + h * D_N + hf * 32);
#pragma unroll
  for (int c = 0; c < 4; ++c) {
    ((uint4*)d0)[c] = make_uint4(w0[4 * c], w0[4 * c + 1], w0[4 * c + 2], w0[4 * c + 3]);
    ((uint4*)d1)[c] = make_uint4(w1[4 * c], w1[4 * c + 1], w1[4 * c + 2], w1[4 * c + 3]);
  }
}

// ---------------------------------------------------------------------------
extern "C" void kernel_launch(void* const* d_in, const int* in_sizes, int n_in,
                              void* d_out, int out_size, void* d_ws, size_t ws_size,
                              hipStream_t stream) {
  const float* x = (const float*)d_in[0];
  const float* w_in = (const float*)d_in[1];
  const float* b_in = (const float*)d_in[2];
  const float* w_out = (const float*)d_in[3];
  const float* b_out = (const float*)d_in[4];
  float* y = (float*)d_out;

  char* ws = (char*)d_ws;
  const size_t qkv_bytes = (size_t)M_N * TC_N * 2;
  const size_t xb_bytes = (size_t)M_N * C_N * 2;
  _Float16* qkv = (_Float16*)ws;
  ushort* xb = (ushort*)(ws + qkv_bytes);
  ushort* attn = xb;  // aliased: xb dead after gemm1
  ushort* winb = (ushort*)(ws + qkv_bytes + xb_bytes);
  ushort* woutb = winb + TC_N * C_N;

  cvt2_f32_bf16_k<<<128, 256, 0, stream>>>(w_in, winb, TC_N * C_N / 4,
                                           w_out, woutb, C_N * C_N / 4);
  cvt_f32_bf16_k<<<2048, 256, 0, stream>>>(x, xb, M_N * C_N / 4);

  gemm_bt<_Float16><<<(M_N / 128) * (TC_N / 128), 256, 0, stream>>>(
      xb, winb, b_in, qkv, TC_N, TC_N / 128, (M_N / 128) * (TC_N / 128) / 8);

  attn_banded<<<BT_N * H_N, 256, 0, stream>>>(qkv, attn);

  gemm_bt<float><<<(M_N / 128) * (C_N / 128), 256, 0, stream>>>(
      attn, woutb, b_out, y, C_N, C_N / 128, (M_N / 128) * (C_N / 128) / 8);
}

// Round 5
// 120.517 us; speedup vs baseline: 1.4257x; 1.1293x over previous
//
#include <hip/hip_runtime.h>
#include <hip/hip_bf16.h>
#include <cstdint>

typedef unsigned int u32;
typedef __attribute__((ext_vector_type(8))) __bf16 bf16x8;
typedef __attribute__((ext_vector_type(4))) float f32x4;
typedef __attribute__((ext_vector_type(2))) _Float16 half2_t;

#define BT_N 256
#define F_N 256
#define C_N 256
#define H_N 4
#define D_N 64
#define TC_N 768
#define M_N (BT_N * F_N)   // 65536

__device__ __forceinline__ ushort f2bf(float f) {
  u32 u = __float_as_uint(f);
  u32 r = (u + 0x7fffu + ((u >> 16) & 1u)) >> 16;
  return (ushort)r;
}

__device__ __forceinline__ half2_t u2h(u32 u) {
  return __builtin_bit_cast(half2_t, u);
}

__device__ __forceinline__ void store_out(_Float16* p, float v) { *p = (_Float16)v; }
__device__ __forceinline__ void store_out(float* p, float v) { *p = v; }

__device__ __forceinline__ void gload_lds16(const ushort* g, ushort* l) {
  __builtin_amdgcn_global_load_lds(
      (const __attribute__((address_space(1))) u32*)g,
      (__attribute__((address_space(3))) u32*)l, 16, 0, 0);
}

// quad_perm XOR-add (VALU-only butterfly within 4-lane groups)
__device__ __forceinline__ float dpp_xor1_add(float x) {
  int t = __builtin_amdgcn_mov_dpp(__builtin_bit_cast(int, x), 0xB1, 0xF, 0xF, true);
  return x + __builtin_bit_cast(float, t);
}
__device__ __forceinline__ float dpp_xor2_add(float x) {
  int t = __builtin_amdgcn_mov_dpp(__builtin_bit_cast(int, x), 0x4E, 0xF, 0xF, true);
  return x + __builtin_bit_cast(float, t);
}

// ---------------------------------------------------------------------------
// fp32 -> bf16 conversion: x, w_in, w_out in ONE launch
// ---------------------------------------------------------------------------
__global__ __launch_bounds__(256) void cvt3_f32_bf16_k(
    const float* __restrict__ sx, ushort* __restrict__ dx, int nx4,
    const float* __restrict__ si, ushort* __restrict__ di, int ni4,
    const float* __restrict__ so, ushort* __restrict__ dq, int no4) {
  int idx = blockIdx.x * 256 + threadIdx.x;
  int stride = gridDim.x * 256;
  int ntot = nx4 + ni4 + no4;
  for (int i = idx; i < ntot; i += stride) {
    const float4* s;
    ushort* d;
    if (i < nx4) { s = (const float4*)sx + i; d = dx + (size_t)i * 4; }
    else if (i < nx4 + ni4) { int k = i - nx4; s = (const float4*)si + k; d = di + (size_t)k * 4; }
    else { int k = i - nx4 - ni4; s = (const float4*)so + k; d = dq + (size_t)k * 4; }
    float4 v = *s;
    u32 a = (u32)f2bf(v.x) | ((u32)f2bf(v.y) << 16);
    u32 b = (u32)f2bf(v.z) | ((u32)f2bf(v.w) << 16);
    *(uint2*)d = make_uint2(a, b);
  }
}

// ---------------------------------------------------------------------------
// GEMM: C[m][n] = sum_k A[m][k]*B[n][k] + bias[n].  K=256 fixed.
// 128x128 tile, BK=64, double-buffered LDS, 2-phase pipeline.
// T2 chunk-XOR swizzle: data(row,chunk) lives at chunk^(row&7) (16B chunks),
// applied via pre-swizzled GLOBAL source (gload_lds writes linearly) and
// XOR'd ds_read chunk.  Epilogue via LDS for coalesced stores.  XCD swizzle.
// ---------------------------------------------------------------------------
template <typename OutT>
__global__ __launch_bounds__(256, 2) void gemm_bt(
    const ushort* __restrict__ Ap, const ushort* __restrict__ Bp,
    const float* __restrict__ bias, OutT* __restrict__ Cp,
    int N, int NTN, int nwg8) {
  constexpr bool F32OUT = (sizeof(OutT) == 4);
  constexpr int SMEM_BYTES = F32OUT ? 67584 : 65536;
  __shared__ char smem[SMEM_BYTES];
  ushort* smemH = (ushort*)smem;

  const int tid = threadIdx.x;
  const int lane = tid & 63;
  const int wid = tid >> 6;
  const int wr = wid >> 1, wc = wid & 1;
  const int l15 = lane & 15, l4 = lane >> 4;
  const int b = blockIdx.x;
  const int bid = (b & 7) * nwg8 + (b >> 3);
  const int tm = bid / NTN;
  const int tn = bid - tm * NTN;
  const int rowBase = tm * 128, colBase = tn * 128;

  f32x4 acc[4][4] = {};

  const int ar = (tid >> 3);
  // pre-swizzled source chunk: dest chunk (tid&7) at row ar must hold
  // global chunk (tid&7) ^ (ar&7)
  const int akk = (((tid & 7) ^ (ar & 7)) << 3);
  const ushort* gA = Ap + (size_t)(rowBase + ar) * 256 + akk;
  const ushort* gB = Bp + (size_t)(colBase + ar) * 256 + akk;

#define STAGE(buf, k0)                                                        \
  {                                                                           \
    ushort* As_ = smemH + (buf) * 8192;                                       \
    ushort* Bs_ = smemH + 16384 + (buf) * 8192;                               \
    _Pragma("unroll") for (int c = 0; c < 4; ++c) {                           \
      gload_lds16(gA + (size_t)(c * 32) * 256 + (k0),                         \
                  As_ + (size_t)(c * 256 + (wid << 6)) * 8);                  \
      gload_lds16(gB + (size_t)(c * 32) * 256 + (k0),                         \
                  Bs_ + (size_t)(c * 256 + (wid << 6)) * 8);                  \
    }                                                                         \
  }

  STAGE(0, 0);
  int cur = 0;
#pragma unroll
  for (int t = 0; t < 4; ++t) {
    __syncthreads();
    if (t < 3) STAGE(cur ^ 1, (t + 1) * 64);
    const ushort* As_ = smemH + cur * 8192;
    const ushort* Bs_ = smemH + 16384 + cur * 8192;
#pragma unroll
    for (int kk = 0; kk < 2; ++kk) {
      bf16x8 af[4];
      bf16x8 bfr[4];
#pragma unroll
      for (int i2 = 0; i2 < 4; ++i2) {
        int row = wr * 64 + i2 * 16 + l15;
        af[i2] = *(const bf16x8*)(As_ + row * 64 + (((kk * 4 + l4) ^ (l15 & 7)) * 8));
      }
#pragma unroll
      for (int j2 = 0; j2 < 4; ++j2) {
        int row = wc * 64 + j2 * 16 + l15;
        bfr[j2] = *(const bf16x8*)(Bs_ + row * 64 + (((kk * 4 + l4) ^ (l15 & 7)) * 8));
      }
#pragma unroll
      for (int i2 = 0; i2 < 4; ++i2)
#pragma unroll
        for (int j2 = 0; j2 < 4; ++j2)
          acc[i2][j2] = __builtin_amdgcn_mfma_f32_16x16x32_bf16(
              af[i2], bfr[j2], acc[i2][j2], 0, 0, 0);
    }
    cur ^= 1;
  }
#undef STAGE

  // ---- epilogue via LDS (coalesced stores) ----
  __syncthreads();
  if constexpr (F32OUT) {
    float* eb = (float*)smem;
#pragma unroll
    for (int j2 = 0; j2 < 4; ++j2) {
      float bv = bias[colBase + wc * 64 + j2 * 16 + l15];
#pragma unroll
      for (int i2 = 0; i2 < 4; ++i2)
#pragma unroll
        for (int r = 0; r < 4; ++r)
          eb[(wr * 64 + i2 * 16 + l4 * 4 + r) * 132 + wc * 64 + j2 * 16 + l15] =
              acc[i2][j2][r] + bv;
    }
    __syncthreads();
#pragma unroll
    for (int i = 0; i < 32; ++i) {
      int row = wid * 32 + i;
      uint2 d = *(const uint2*)((const u32*)eb + row * 132 + lane * 2);
      *(uint2*)((float*)Cp + (size_t)(rowBase + row) * N + colBase + lane * 2) = d;
    }
  } else {
    ushort* eb = smemH;
#pragma unroll
    for (int j2 = 0; j2 < 4; ++j2) {
      float bv = bias[colBase + wc * 64 + j2 * 16 + l15];
#pragma unroll
      for (int i2 = 0; i2 < 4; ++i2)
#pragma unroll
        for (int r = 0; r < 4; ++r) {
          _Float16 h = (_Float16)(acc[i2][j2][r] + bv);
          eb[(wr * 64 + i2 * 16 + l4 * 4 + r) * 136 + wc * 64 + j2 * 16 + l15] =
              __builtin_bit_cast(ushort, h);
        }
    }
    __syncthreads();
#pragma unroll
    for (int i = 0; i < 16; ++i) {
      int row = wid * 32 + 2 * i + (lane >> 5);
      int hl = lane & 31;
      uint2 d = *(const uint2*)(eb + row * 136 + hl * 4);
      *(uint2*)((_Float16*)Cp + (size_t)(rowBase + row) * N + colBase + hl * 4) = d;
    }
  }
}

// ---------------------------------------------------------------------------
// Banded attention: one block per (bt, h).  256 threads.
// 4-lane group (q = tid>>2) owns rows 4q..4q+3; lane s = tid&3 owns dim
// quarter halves [s*16, s*16+16).  Window loop jo=0..35 (j = 4q-16+jo),
// each lane reads 2+2 ds_read_b128 (K,V) per iter.
// K/V LDS: [256 rows][128B], chunk c stored at c ^ ((r>>2)&7)  -> balanced
// banks (8 lanes per 16B chunk-group = inherent minimum).
// Quad reduce via DPP quad_perm (no LDS-pipe shuffles).
// ---------------------------------------------------------------------------
__global__ __launch_bounds__(256) void attn_banded(
    const _Float16* __restrict__ qkv, ushort* __restrict__ aout) {
  __shared__ uint4 kbuf4[256 * 8];
  __shared__ uint4 vbuf4[256 * 8];
  const int tid = threadIdx.x;
  const int bt = blockIdx.x >> 2;
  const int h = blockIdx.x & 3;
  const _Float16* base = qkv + (size_t)bt * F_N * TC_N + h * D_N;

  // stage K,V (swizzled chunk write)
  {
    const int r0 = tid >> 3;
    const int c = tid & 7;
    const int cs = c ^ ((tid >> 5) & 7);  // (r>>2)&7 == (tid>>5)&7 (+p*8 = 0 mod 8)
#pragma unroll
    for (int p = 0; p < 8; ++p) {
      int r = p * 32 + r0;
      uint4 k4 = *(const uint4*)(base + (size_t)r * TC_N + 256 + c * 8);
      uint4 v4 = *(const uint4*)(base + (size_t)r * TC_N + 512 + c * 8);
      kbuf4[r * 8 + cs] = k4;
      vbuf4[r * 8 + cs] = v4;
    }
  }

  const int q = tid >> 2;
  const int s = tid & 3;

  // load Q quarters: 4 rows x 16 halves
  half2_t qh[4][8];
#pragma unroll
  for (int ii = 0; ii < 4; ++ii) {
    const uint4* gq = (const uint4*)(base + (size_t)(4 * q + ii) * TC_N + s * 16);
    uint4 a = gq[0], b2 = gq[1];
    qh[ii][0] = u2h(a.x); qh[ii][1] = u2h(a.y); qh[ii][2] = u2h(a.z); qh[ii][3] = u2h(a.w);
    qh[ii][4] = u2h(b2.x); qh[ii][5] = u2h(b2.y); qh[ii][6] = u2h(b2.z); qh[ii][7] = u2h(b2.w);
  }
  __syncthreads();

  float l[4] = {0.f, 0.f, 0.f, 0.f};
  half2_t o[4][8];
  const _Float16 z0 = (_Float16)0.f;
#pragma unroll
  for (int ii = 0; ii < 4; ++ii)
#pragma unroll
    for (int m = 0; m < 8; ++m) o[ii][m] = half2_t{z0, z0};

#pragma unroll 4
  for (int jo = 0; jo < 36; ++jo) {
    int j = 4 * q - 16 + jo;
    int jc = j < 0 ? 0 : (j > 255 ? 255 : j);
    int cb = (jc >> 2) & 7;
    const uint4* krow = kbuf4 + jc * 8;
    uint4 ka = krow[(2 * s) ^ cb];
    uint4 kb = krow[(2 * s + 1) ^ cb];
    half2_t kh[8];
    kh[0] = u2h(ka.x); kh[1] = u2h(ka.y); kh[2] = u2h(ka.z); kh[3] = u2h(ka.w);
    kh[4] = u2h(kb.x); kh[5] = u2h(kb.y); kh[6] = u2h(kb.z); kh[7] = u2h(kb.w);

    float dv[4];
#pragma unroll
    for (int ii = 0; ii < 4; ++ii) {
      float a0 = 0.f, a1 = 0.f;
#pragma unroll
      for (int m = 0; m < 4; ++m) {
        a0 = __builtin_amdgcn_fdot2(kh[2 * m], qh[ii][2 * m], a0, false);
        a1 = __builtin_amdgcn_fdot2(kh[2 * m + 1], qh[ii][2 * m + 1], a1, false);
      }
      dv[ii] = a0 + a1;
    }
#pragma unroll
    for (int ii = 0; ii < 4; ++ii) {
      dv[ii] = dpp_xor1_add(dv[ii]);
      dv[ii] = dpp_xor2_add(dv[ii]);
    }

    bool okj = (j >= 0) && (j < 256);
    float p[4];
    p[0] = (okj && jo <= 32) ? __expf(dv[0] * 0.125f) : 0.f;
    p[1] = (okj && jo >= 1 && jo <= 33) ? __expf(dv[1] * 0.125f) : 0.f;
    p[2] = (okj && jo >= 2 && jo <= 34) ? __expf(dv[2] * 0.125f) : 0.f;
    p[3] = (okj && jo >= 3) ? __expf(dv[3] * 0.125f) : 0.f;

    const uint4* vrow = vbuf4 + jc * 8;
    uint4 va = vrow[(2 * s) ^ cb];
    uint4 vb = vrow[(2 * s + 1) ^ cb];
    half2_t vh[8];
    vh[0] = u2h(va.x); vh[1] = u2h(va.y); vh[2] = u2h(va.z); vh[3] = u2h(va.w);
    vh[4] = u2h(vb.x); vh[5] = u2h(vb.y); vh[6] = u2h(vb.z); vh[7] = u2h(vb.w);

#pragma unroll
    for (int ii = 0; ii < 4; ++ii) {
      l[ii] += p[ii];
      _Float16 pf = (_Float16)p[ii];
      half2_t ph = {pf, pf};
#pragma unroll
      for (int m = 0; m < 8; ++m) o[ii][m] = vh[m] * ph + o[ii][m];
    }
  }

#pragma unroll
  for (int ii = 0; ii < 4; ++ii) {
    float inv = 1.f / l[ii];
    u32 w[4];
#pragma unroll
    for (int m = 0; m < 4; ++m) {
      float f0 = (float)o[ii][2 * m][0] * inv;
      float f1 = (float)o[ii][2 * m][1] * inv;
      float f2 = (float)o[ii][2 * m + 1][0] * inv;
      float f3 = (float)o[ii][2 * m + 1][1] * inv;
      w[m] = 0;  // silence
      w[m] = (u32)f2bf(f0) | ((u32)f2bf(f1) << 16);
      ((u32*)w)[m] = w[m];
      u32 hi = (u32)f2bf(f2) | ((u32)f2bf(f3) << 16);
      if (m & 1) { }
      // pack 2 dwords per m-pair handled below
      w[m] = w[m];  // keep
      // store both dwords directly:
      u32* dst = (u32*)(aout + (size_t)(bt * F_N + 4 * q + ii) * C_N + h * D_N + s * 16) + 2 * m;
      dst[0] = w[m];
      dst[1] = hi;
    }
  }
}

// ---------------------------------------------------------------------------
extern "C" void kernel_launch(void* const* d_in, const int* in_sizes, int n_in,
                              void* d_out, int out_size, void* d_ws, size_t ws_size,
                              hipStream_t stream) {
  const float* x = (const float*)d_in[0];
  const float* w_in = (const float*)d_in[1];
  const float* b_in = (const float*)d_in[2];
  const float* w_out = (const float*)d_in[3];
  const float* b_out = (const float*)d_in[4];
  float* y = (float*)d_out;

  char* ws = (char*)d_ws;
  const size_t qkv_bytes = (size_t)M_N * TC_N * 2;
  const size_t xb_bytes = (size_t)M_N * C_N * 2;
  _Float16* qkv = (_Float16*)ws;
  ushort* xb = (ushort*)(ws + qkv_bytes);
  ushort* attn = xb;  // aliased: xb dead after gemm1
  ushort* winb = (ushort*)(ws + qkv_bytes + xb_bytes);
  ushort* woutb = winb + TC_N * C_N;

  cvt3_f32_bf16_k<<<2048, 256, 0, stream>>>(x, xb, M_N * C_N / 4,
                                            w_in, winb, TC_N * C_N / 4,
                                            w_out, woutb, C_N * C_N / 4);

  gemm_bt<_Float16><<<(M_N / 128) * (TC_N / 128), 256, 0, stream>>>(
      xb, winb, b_in, qkv, TC_N, TC_N / 128, (M_N / 128) * (TC_N / 128) / 8);

  attn_banded<<<BT_N * H_N, 256, 0, stream>>>(qkv, attn);

  gemm_bt<float><<<(M_N / 128) * (C_N / 128), 256, 0, stream>>>(
      attn, woutb, b_out, y, C_N, C_N / 128, (M_N / 128) * (C_N / 128) / 8);
}

// Round 9
// 102.897 us; speedup vs baseline: 1.6698x; 1.1712x over previous
//
#include <hip/hip_runtime.h>
#include <hip/hip_bf16.h>
#include <cstdint>

typedef unsigned int u32;
typedef __attribute__((ext_vector_type(8))) __bf16 bf16x8;
typedef __attribute__((ext_vector_type(4))) float f32x4;
typedef __attribute__((ext_vector_type(2))) _Float16 half2_t;
typedef __attribute__((ext_vector_type(4))) _Float16 half4;
typedef __attribute__((ext_vector_type(2))) __fp16 fp16x2;

#define BT_N 256
#define F_N 256
#define C_N 256
#define H_N 4
#define D_N 64
#define TC_N 768
#define M_N (BT_N * F_N)   // 65536
#define VT_ST 268          // vt row stride (halves): 8B-aligned rows, spread banks

__device__ __forceinline__ ushort f2bf(float f) {
  u32 u = __float_as_uint(f);
  u32 r = (u + 0x7fffu + ((u >> 16) & 1u)) >> 16;
  return (ushort)r;
}

__device__ __forceinline__ void gload_lds16(const ushort* g, ushort* l) {
  __builtin_amdgcn_global_load_lds(
      (const __attribute__((address_space(1))) u32*)g,
      (__attribute__((address_space(3))) u32*)l, 16, 0, 0);
}

// ---------------------------------------------------------------------------
// fp32 -> bf16 conversion: x, w_in, w_out in ONE launch
// ---------------------------------------------------------------------------
__global__ __launch_bounds__(256) void cvt3_f32_bf16_k(
    const float* __restrict__ sx, ushort* __restrict__ dx, int nx4,
    const float* __restrict__ si, ushort* __restrict__ di, int ni4,
    const float* __restrict__ so, ushort* __restrict__ dq, int no4) {
  int idx = blockIdx.x * 256 + threadIdx.x;
  int stride = gridDim.x * 256;
  int ntot = nx4 + ni4 + no4;
  for (int i = idx; i < ntot; i += stride) {
    const float4* s;
    ushort* d;
    if (i < nx4) { s = (const float4*)sx + i; d = dx + (size_t)i * 4; }
    else if (i < nx4 + ni4) { int k = i - nx4; s = (const float4*)si + k; d = di + (size_t)k * 4; }
    else { int k = i - nx4 - ni4; s = (const float4*)so + k; d = dq + (size_t)k * 4; }
    float4 v = *s;
    u32 a = (u32)f2bf(v.x) | ((u32)f2bf(v.y) << 16);
    u32 b = (u32)f2bf(v.z) | ((u32)f2bf(v.w) << 16);
    *(uint2*)d = make_uint2(a, b);
  }
}

// ---------------------------------------------------------------------------
// GEMM: C[m][n] = sum_k A[m][k]*B[n][k] + bias[n].  K=256 fixed.  (unchanged)
// ---------------------------------------------------------------------------
template <typename OutT>
__global__ __launch_bounds__(256, 2) void gemm_bt(
    const ushort* __restrict__ Ap, const ushort* __restrict__ Bp,
    const float* __restrict__ bias, OutT* __restrict__ Cp,
    int N, int NTN, int nwg8) {
  constexpr bool F32OUT = (sizeof(OutT) == 4);
  constexpr int SMEM_BYTES = F32OUT ? 67584 : 65536;
  __shared__ char smem[SMEM_BYTES];
  ushort* smemH = (ushort*)smem;

  const int tid = threadIdx.x;
  const int lane = tid & 63;
  const int wid = tid >> 6;
  const int wr = wid >> 1, wc = wid & 1;
  const int l15 = lane & 15, l4 = lane >> 4;
  const int b = blockIdx.x;
  const int bid = (b & 7) * nwg8 + (b >> 3);
  const int tm = bid / NTN;
  const int tn = bid - tm * NTN;
  const int rowBase = tm * 128, colBase = tn * 128;

  f32x4 acc[4][4] = {};

  const int ar = (tid >> 3);
  const int akk = (((tid & 7) ^ (ar & 7)) << 3);
  const ushort* gA = Ap + (size_t)(rowBase + ar) * 256 + akk;
  const ushort* gB = Bp + (size_t)(colBase + ar) * 256 + akk;

#define STAGE(buf, k0)                                                        \
  {                                                                           \
    ushort* As_ = smemH + (buf) * 8192;                                       \
    ushort* Bs_ = smemH + 16384 + (buf) * 8192;                               \
    _Pragma("unroll") for (int c = 0; c < 4; ++c) {                           \
      gload_lds16(gA + (size_t)(c * 32) * 256 + (k0),                         \
                  As_ + (size_t)(c * 256 + (wid << 6)) * 8);                  \
      gload_lds16(gB + (size_t)(c * 32) * 256 + (k0),                         \
                  Bs_ + (size_t)(c * 256 + (wid << 6)) * 8);                  \
    }                                                                         \
  }

  STAGE(0, 0);
  int cur = 0;
#pragma unroll
  for (int t = 0; t < 4; ++t) {
    __syncthreads();
    if (t < 3) STAGE(cur ^ 1, (t + 1) * 64);
    const ushort* As_ = smemH + cur * 8192;
    const ushort* Bs_ = smemH + 16384 + cur * 8192;
#pragma unroll
    for (int kk = 0; kk < 2; ++kk) {
      bf16x8 af[4];
      bf16x8 bfr[4];
#pragma unroll
      for (int i2 = 0; i2 < 4; ++i2) {
        int row = wr * 64 + i2 * 16 + l15;
        af[i2] = *(const bf16x8*)(As_ + row * 64 + (((kk * 4 + l4) ^ (l15 & 7)) * 8));
      }
#pragma unroll
      for (int j2 = 0; j2 < 4; ++j2) {
        int row = wc * 64 + j2 * 16 + l15;
        bfr[j2] = *(const bf16x8*)(Bs_ + row * 64 + (((kk * 4 + l4) ^ (l15 & 7)) * 8));
      }
#pragma unroll
      for (int i2 = 0; i2 < 4; ++i2)
#pragma unroll
        for (int j2 = 0; j2 < 4; ++j2)
          acc[i2][j2] = __builtin_amdgcn_mfma_f32_16x16x32_bf16(
              af[i2], bfr[j2], acc[i2][j2], 0, 0, 0);
    }
    cur ^= 1;
  }
#undef STAGE

  __syncthreads();
  if constexpr (F32OUT) {
    float* eb = (float*)smem;
#pragma unroll
    for (int j2 = 0; j2 < 4; ++j2) {
      float bv = bias[colBase + wc * 64 + j2 * 16 + l15];
#pragma unroll
      for (int i2 = 0; i2 < 4; ++i2)
#pragma unroll
        for (int r = 0; r < 4; ++r)
          eb[(wr * 64 + i2 * 16 + l4 * 4 + r) * 132 + wc * 64 + j2 * 16 + l15] =
              acc[i2][j2][r] + bv;
    }
    __syncthreads();
#pragma unroll
    for (int i = 0; i < 32; ++i) {
      int row = wid * 32 + i;
      uint2 d = *(const uint2*)((const u32*)eb + row * 132 + lane * 2);
      *(uint2*)((float*)Cp + (size_t)(rowBase + row) * N + colBase + lane * 2) = d;
    }
  } else {
    ushort* eb = smemH;
#pragma unroll
    for (int j2 = 0; j2 < 4; ++j2) {
      float bv = bias[colBase + wc * 64 + j2 * 16 + l15];
#pragma unroll
      for (int i2 = 0; i2 < 4; ++i2)
#pragma unroll
        for (int r = 0; r < 4; ++r) {
          _Float16 h = (_Float16)(acc[i2][j2][r] + bv);
          eb[(wr * 64 + i2 * 16 + l4 * 4 + r) * 136 + wc * 64 + j2 * 16 + l15] =
              __builtin_bit_cast(ushort, h);
        }
    }
    __syncthreads();
#pragma unroll
    for (int i = 0; i < 16; ++i) {
      int row = wid * 32 + 2 * i + (lane >> 5);
      int hl = lane & 31;
      uint2 d = *(const uint2*)(eb + row * 136 + hl * 4);
      *(uint2*)((_Float16*)Cp + (size_t)(rowBase + row) * N + colBase + hl * 4) = d;
    }
  }
}

// ---------------------------------------------------------------------------
// Banded attention via MFMA.  One block per (bt,h); 4 waves; wave w owns
// Q rows [64w,64w+64) as 4 row-tiles of 16.  Per row-tile (R0):
//   window keys [R0-16, R0+32) = 3 tiles of 16
//   S^T = mfma16x16x16f16(A=K, B=Q): st[jt][r] = S[q=R0+l15][key=Jc+16jt+g4+r]
//   softmax in-register (band bitmask; no max-subtract; sum via shfl 16/32;
//   1/l folded into P)
//   out^T = mfma(A=V^T, B=P^T): P^T B-frag == softmaxed S^T C-frag (free);
//   V^T A-frag = plain ds_read_b64 from explicitly transposed vt[d][j] in LDS.
// LDS: K [256][72] halves; vt [64][VT_ST] halves (vt[d*VT_ST+j] = V[j][d]).
// ---------------------------------------------------------------------------
__global__ __launch_bounds__(256) void attn_mfma(
    const _Float16* __restrict__ qkv, ushort* __restrict__ aout) {
  __shared__ ushort smem[18432 + 64 * VT_ST];
  const int tid = threadIdx.x;
  const int bt = blockIdx.x >> 2;
  const int h = blockIdx.x & 3;
  const _Float16* base = qkv + (size_t)bt * 256 * 768 + h * 64;
  ushort* klds = smem;
  ushort* vlds = smem + 18432;

  // ---- stage K (stride 72) and V transposed (vt[d][j], scalar scatter) ----
  {
    const int r0 = tid >> 3, c8 = tid & 7;
#pragma unroll
    for (int p = 0; p < 8; ++p) {
      int j = p * 32 + r0;
      const uint4 k4 = *(const uint4*)(base + (size_t)j * 768 + 256 + c8 * 8);
      *(uint4*)(klds + j * 72 + c8 * 8) = k4;
      const uint4 v4 = *(const uint4*)(base + (size_t)j * 768 + 512 + c8 * 8);
      const ushort* vh = (const ushort*)&v4;
      ushort* vtp = vlds + (c8 * 8) * VT_ST + j;
#pragma unroll
      for (int i = 0; i < 8; ++i) vtp[i * VT_ST] = vh[i];
    }
  }

  const int w = tid >> 6, lane = tid & 63;
  const int l15 = lane & 15, g = lane >> 4, g4 = g * 4;

  // Q B-frags for all 4 row-tiles (global reads, pre-barrier)
  uint2 qf0[4], qf1[4], qf2[4], qf3[4];
  {
    const uint2* q0 = (const uint2*)(base + (size_t)(w * 64 + 0 * 16 + l15) * 768 + g4);
    const uint2* q1 = (const uint2*)(base + (size_t)(w * 64 + 1 * 16 + l15) * 768 + g4);
    const uint2* q2 = (const uint2*)(base + (size_t)(w * 64 + 2 * 16 + l15) * 768 + g4);
    const uint2* q3 = (const uint2*)(base + (size_t)(w * 64 + 3 * 16 + l15) * 768 + g4);
#pragma unroll
    for (int ks = 0; ks < 4; ++ks) {
      qf0[ks] = q0[ks * 4]; qf1[ks] = q1[ks * 4];
      qf2[ks] = q2[ks * 4]; qf3[ks] = q3[ks * 4];
    }
  }

  // band-mask bits: keep(jt,r) iff |16jt+g4+r-16-l15| <= 16
  u32 bb = 0;
#pragma unroll
  for (int jt = 0; jt < 3; ++jt)
#pragma unroll
    for (int r = 0; r < 4; ++r) {
      int d = 16 * jt + g4 + r - 16 - l15;
      if (d >= -16 && d <= 16) bb |= 1u << (jt * 4 + r);
    }

  __syncthreads();

  const float SC = 0.18033688f;  // 0.125 * log2(e)

#pragma unroll
  for (int rt = 0; rt < 4; ++rt) {
    const int R0 = w * 64 + rt * 16;
    const int Jc = R0 - 16;
    const uint2* qf = (rt == 0) ? qf0 : (rt == 1) ? qf1 : (rt == 2) ? qf2 : qf3;

    // ---- S^T = K . Q^T ----
    f32x4 st[3] = {};
#pragma unroll
    for (int jt = 0; jt < 3; ++jt) {
      int krow = Jc + 16 * jt + l15;
      krow = krow < 0 ? 0 : (krow > 255 ? 255 : krow);
      const ushort* kp = klds + krow * 72 + g4;
#pragma unroll
      for (int ks = 0; ks < 4; ++ks) {
        uint2 kf = *(const uint2*)(kp + ks * 16);
        st[jt] = __builtin_amdgcn_mfma_f32_16x16x16f16(
            __builtin_bit_cast(half4, kf), __builtin_bit_cast(half4, qf[ks]),
            st[jt], 0, 0, 0);
      }
    }

    // ---- softmax ----
    float l_acc = 0.f;
    float pp[3][4];
#pragma unroll
    for (int jt = 0; jt < 3; ++jt)
#pragma unroll
      for (int r = 0; r < 4; ++r) {
        int jg = Jc + 16 * jt + g4 + r;
        bool keep = (((bb >> (jt * 4 + r)) & 1u) != 0) && (jg >= 0) && (jg < 256);
        float pv = keep ? __builtin_amdgcn_exp2f(st[jt][r] * SC) : 0.f;
        pp[jt][r] = pv;
        l_acc += pv;
      }
    l_acc += __shfl_xor(l_acc, 16, 64);
    l_acc += __shfl_xor(l_acc, 32, 64);
    const float inv = 1.f / l_acc;

    uint2 pf[3];
#pragma unroll
    for (int jt = 0; jt < 3; ++jt) {
      fp16x2 a = __builtin_amdgcn_cvt_pkrtz(pp[jt][0] * inv, pp[jt][1] * inv);
      fp16x2 c = __builtin_amdgcn_cvt_pkrtz(pp[jt][2] * inv, pp[jt][3] * inv);
      pf[jt].x = __builtin_bit_cast(u32, a);
      pf[jt].y = __builtin_bit_cast(u32, c);
    }

    // ---- out^T = V^T . P^T ----
    // A-frag lane l: V^T[dv=16mt+l15][keys jb..jb+3] = vt[(16mt+l15)*VT_ST + jb]
    f32x4 ot[4] = {};
#pragma unroll
    for (int kt = 0; kt < 3; ++kt) {
      int jb = Jc + 16 * kt + g4;
      jb = jb < 0 ? 0 : (jb > 252 ? 252 : jb);
#pragma unroll
      for (int mt = 0; mt < 4; ++mt) {
        uint2 vfr = *(const uint2*)(vlds + (16 * mt + l15) * VT_ST + jb);
        ot[mt] = __builtin_amdgcn_mfma_f32_16x16x16f16(
            __builtin_bit_cast(half4, vfr), __builtin_bit_cast(half4, pf[kt]),
            ot[mt], 0, 0, 0);
      }
    }

    // ---- store bf16: ot[mt][r] = out[q=R0+l15][dv=16mt+g4+r] ----
    ushort* orow = aout + (size_t)(bt * 256 + R0 + l15) * 256 + h * 64 + g4;
#pragma unroll
    for (int mt = 0; mt < 4; ++mt) {
      u32 lo = (u32)f2bf(ot[mt][0]) | ((u32)f2bf(ot[mt][1]) << 16);
      u32 hi = (u32)f2bf(ot[mt][2]) | ((u32)f2bf(ot[mt][3]) << 16);
      *(uint2*)(orow + mt * 16) = make_uint2(lo, hi);
    }
  }
}

// ---------------------------------------------------------------------------
extern "C" void kernel_launch(void* const* d_in, const int* in_sizes, int n_in,
                              void* d_out, int out_size, void* d_ws, size_t ws_size,
                              hipStream_t stream) {
  const float* x = (const float*)d_in[0];
  const float* w_in = (const float*)d_in[1];
  const float* b_in = (const float*)d_in[2];
  const float* w_out = (const float*)d_in[3];
  const float* b_out = (const float*)d_in[4];
  float* y = (float*)d_out;

  char* ws = (char*)d_ws;
  const size_t qkv_bytes = (size_t)M_N * TC_N * 2;
  const size_t xb_bytes = (size_t)M_N * C_N * 2;
  _Float16* qkv = (_Float16*)ws;
  ushort* xb = (ushort*)(ws + qkv_bytes);
  ushort* attn = xb;  // aliased: xb dead after gemm1
  ushort* winb = (ushort*)(ws + qkv_bytes + xb_bytes);
  ushort* woutb = winb + TC_N * C_N;

  cvt3_f32_bf16_k<<<2048, 256, 0, stream>>>(x, xb, M_N * C_N / 4,
                                            w_in, winb, TC_N * C_N / 4,
                                            w_out, woutb, C_N * C_N / 4);

  gemm_bt<_Float16><<<(M_N / 128) * (TC_N / 128), 256, 0, stream>>>(
      xb, winb, b_in, qkv, TC_N, TC_N / 128, (M_N / 128) * (TC_N / 128) / 8);

  attn_mfma<<<BT_N * H_N, 256, 0, stream>>>(qkv, attn);

  gemm_bt<float><<<(M_N / 128) * (C_N / 128), 256, 0, stream>>>(
      attn, woutb, b_out, y, C_N, C_N / 128, (M_N / 128) * (C_N / 128) / 8);
}